// Round 1
// baseline (3245.923 us; speedup 1.0000x reference)
//
#include <hip/hip_runtime.h>

// LinearRNNwithSoftExp on MI355X (gfx950)
// T=1024, B=512, D=128, H=256.
// Design: 256 wgs x 256 threads (4 waves, 1 wave/SIMD, ~1 wg/CU).
// wg g owns batch rows {2g, 2g+1}; fully independent serial recurrence per wg
// (no grid sync). hh_w kept entirely in VGPRs as bf16 MFMA B-fragments.
// h-state: bf16 hi+lo split (2 MFMA passes) for precision; LDS ping-pong
// broadcast of h between waves, one __syncthreads per step.
// x-projection (data @ ih_w^T) fused into the loop with 1-step prefetch.

#define TT 1024
#define BB 512
#define DD 128
#define HH 256

typedef __attribute__((ext_vector_type(8))) short bf16x8;
typedef __attribute__((ext_vector_type(4))) float f32x4;

static __device__ __forceinline__ short f2bf(float f) {
    unsigned u = __float_as_uint(f);
    u += 0x7FFFu + ((u >> 16) & 1u);   // round-to-nearest-even
    return (short)(u >> 16);
}
static __device__ __forceinline__ float bf2f(short s) {
    return __uint_as_float(((unsigned)(unsigned short)s) << 16);
}
static __device__ __forceinline__ bf16x8 pack8(const float4 a, const float4 b) {
    bf16x8 v;
    v[0] = f2bf(a.x); v[1] = f2bf(a.y); v[2] = f2bf(a.z); v[3] = f2bf(a.w);
    v[4] = f2bf(b.x); v[5] = f2bf(b.y); v[6] = f2bf(b.z); v[7] = f2bf(b.w);
    return v;
}

__global__ __launch_bounds__(256, 1)
void rnn_fused(const float* __restrict__ data, const float* __restrict__ ih_w,
               const float* __restrict__ ih_b, const float* __restrict__ hh_w,
               const float* __restrict__ hh_b, const int* __restrict__ lengths,
               float* __restrict__ out)
{
    const int g    = blockIdx.x;
    const int tid  = threadIdx.x;
    const int w    = tid >> 6;     // wave 0..3
    const int lane = tid & 63;
    const int col  = lane & 15;    // MFMA n-col / A-row index
    const int quad = lane >> 4;    // k-quad

    // [pingpong][hi/lo][row(2)][k(256)+8 pad] ; pad -> 528B row stride, 2-way
    // bank aliasing only (free on CDNA4).
    __shared__ short hbuf[2][2][2][264];

    // ---- persistent weight fragments in registers ----
    // whh tiles 0..3 = alpha rows [64w+16t), tiles 4..7 = hbar rows 256+...
    bf16x8 whh[8][8];
    #pragma unroll
    for (int tt = 0; tt < 8; ++tt) {
        const int wrow = (tt < 4 ? 64*w + 16*tt : 256 + 64*w + 16*(tt-4)) + col;
        const float* src = hh_w + wrow * HH;
        #pragma unroll
        for (int i = 0; i < 8; ++i) {
            const float4 a = *(const float4*)(src + i*32 + quad*8);
            const float4 b = *(const float4*)(src + i*32 + quad*8 + 4);
            whh[tt][i] = pack8(a, b);
        }
    }
    bf16x8 wih[4][4];
    #pragma unroll
    for (int x = 0; x < 4; ++x) {
        const int wrow = 64*w + 16*x + col;
        const float* src = ih_w + wrow * DD;
        #pragma unroll
        for (int i = 0; i < 4; ++i) {
            const float4 a = *(const float4*)(src + i*32 + quad*8);
            const float4 b = *(const float4*)(src + i*32 + quad*8 + 4);
            wih[x][i] = pack8(a, b);
        }
    }

    float bA[4], bHh[4], bX[4];
    #pragma unroll
    for (int t4 = 0; t4 < 4; ++t4) {
        bA[t4]  = hh_b[      64*w + 16*t4 + col];
        bHh[t4] = hh_b[256 + 64*w + 16*t4 + col];
        bX[t4]  = ih_b[      64*w + 16*t4 + col];
    }

    const int L0 = lengths[2*g];
    const int L1 = lengths[2*g + 1];
    const int Lmax = (L0 > L1) ? L0 : L1;

    if (tid < 256) {  // zero h state (ping buffer 0), rows 0/1, hi+lo
        hbuf[0][0][0][tid] = 0; hbuf[0][0][1][tid] = 0;
        hbuf[0][1][0][tid] = 0; hbuf[0][1][1][tid] = 0;
    }

    float  nh[4][2] = {{0.f,0.f},{0.f,0.f},{0.f,0.f},{0.f,0.f}};
    bf16x8 af[8] = {};   // h A-frags (masked lanes stay 0 forever)
    bf16x8 dh[4] = {};   // data A-frags (bf16)

    const bool act   = (col < 2);        // only A-rows 0,1 are real
    const int  myrow = 2*g + col;        // batch row for this A-row

    if (act) {  // data for t=0
        const float* dptr = data + myrow * DD;
        #pragma unroll
        for (int i = 0; i < 4; ++i) {
            const float4 a = *(const float4*)(dptr + i*32 + quad*8);
            const float4 b = *(const float4*)(dptr + i*32 + quad*8 + 4);
            dh[i] = pack8(a, b);
        }
    }
    __syncthreads();

    for (int t = 0; t < Lmax; ++t) {
        const int p = t & 1;

        // ---- x-projection for this step (fills MFMA pipe early) ----
        f32x4 xacc[4];
        #pragma unroll
        for (int x = 0; x < 4; ++x) {
            f32x4 v = {bX[x], bX[x], bX[x], bX[x]}; xacc[x] = v;
        }
        #pragma unroll
        for (int i = 0; i < 4; ++i)
            #pragma unroll
            for (int x = 0; x < 4; ++x)
                xacc[x] = __builtin_amdgcn_mfma_f32_16x16x32_bf16(
                    dh[i], wih[x][i], xacc[x], 0, 0, 0);

        // ---- prefetch raw data for step t+1 (latency hidden by MFMAs) ----
        float4 fa[4], fb[4];
        const bool pf = act && (t + 1 < Lmax);
        if (pf) {
            const float* dptr = data + ((t+1)*BB + myrow) * DD;
            #pragma unroll
            for (int i = 0; i < 4; ++i) {
                fa[i] = *(const float4*)(dptr + i*32 + quad*8);
                fb[i] = *(const float4*)(dptr + i*32 + quad*8 + 4);
            }
        }

        // ---- recurrent matmul: hid = h @ hh_w^T + hh_b (hi pass, lo pass) ----
        f32x4 racc[8];
        #pragma unroll
        for (int t4 = 0; t4 < 4; ++t4) {
            f32x4 va = {bA[t4],  bA[t4],  bA[t4],  bA[t4]};  racc[t4]     = va;
            f32x4 vh = {bHh[t4], bHh[t4], bHh[t4], bHh[t4]}; racc[t4 + 4] = vh;
        }
        if (act) {
            #pragma unroll
            for (int i = 0; i < 8; ++i)
                af[i] = *(const bf16x8*)&hbuf[p][0][col][i*32 + quad*8];
        }
        #pragma unroll
        for (int i = 0; i < 8; ++i)
            #pragma unroll
            for (int tt = 0; tt < 8; ++tt)
                racc[tt] = __builtin_amdgcn_mfma_f32_16x16x32_bf16(
                    af[i], whh[tt][i], racc[tt], 0, 0, 0);
        if (act) {
            #pragma unroll
            for (int i = 0; i < 8; ++i)
                af[i] = *(const bf16x8*)&hbuf[p][1][col][i*32 + quad*8];
        }
        #pragma unroll
        for (int i = 0; i < 8; ++i)
            #pragma unroll
            for (int tt = 0; tt < 8; ++tt)
                racc[tt] = __builtin_amdgcn_mfma_f32_16x16x32_bf16(
                    af[i], whh[tt][i], racc[tt], 0, 0, 0);

        // ---- epilogue: sigmoid, soft-exp gate, tanh, masked update ----
        // C/D layout: col = lane&15, row = quad*4 + reg; real rows 0,1 live in
        // quad 0, regs 0,1. Other lanes compute garbage that is never stored.
        #pragma unroll
        for (int t4 = 0; t4 < 4; ++t4) {
            #pragma unroll
            for (int r = 0; r < 2; ++r) {
                const float a   = racc[t4][r];
                const float hv  = racc[t4 + 4][r];
                const float e   = __builtin_amdgcn_exp2f(a * -1.4426950408889634f);
                const float inv = 1.0f + e;                    // exactly 1/alpha
                const float al  = __builtin_amdgcn_rcpf(inv);  // alpha
                const float pp  = __builtin_amdgcn_exp2f(al * hv);
                const float gg  = (pp - 1.0f) * inv + al;
                const float u   = xacc[t4][r] + gg;
                const float t2  = __builtin_amdgcn_exp2f(u * 2.8853900817779268f);
                const float th  = 1.0f - 2.0f * __builtin_amdgcn_rcpf(1.0f + t2);
                const int   Lr  = r ? L1 : L0;
                const float v   = (t < Lr) ? th : nh[t4][r];
                nh[t4][r] = v;
                if (quad == 0) {
                    const short hi = f2bf(v);
                    const short lo = f2bf(v - bf2f(hi));
                    hbuf[1 - p][0][r][64*w + 16*t4 + col] = hi;
                    hbuf[1 - p][1][r][64*w + 16*t4 + col] = lo;
                }
            }
        }

        // ---- convert prefetched data (loads long since landed) ----
        if (pf) {
            #pragma unroll
            for (int i = 0; i < 4; ++i) dh[i] = pack8(fa[i], fb[i]);
        }
        __syncthreads();
    }

    // ---- final hidden state -> out [1, B, H] fp32 ----
    if (quad == 0) {
        #pragma unroll
        for (int t4 = 0; t4 < 4; ++t4)
            #pragma unroll
            for (int r = 0; r < 2; ++r)
                out[(2*g + r) * HH + 64*w + 16*t4 + col] = nh[t4][r];
    }
}

extern "C" void kernel_launch(void* const* d_in, const int* in_sizes, int n_in,
                              void* d_out, int out_size, void* d_ws, size_t ws_size,
                              hipStream_t stream) {
    const float* data    = (const float*)d_in[0];
    const float* ih_w    = (const float*)d_in[1];
    const float* ih_b    = (const float*)d_in[2];
    const float* hh_w    = (const float*)d_in[3];
    const float* hh_b    = (const float*)d_in[4];
    const int*   lengths = (const int*)d_in[5];
    float* out = (float*)d_out;

    (void)in_sizes; (void)n_in; (void)out_size; (void)d_ws; (void)ws_size;

    rnn_fused<<<dim3(BB / 2), dim3(256), 0, stream>>>(
        data, ih_w, ih_b, hh_w, hh_b, lengths, out);
}

// Round 2
// 1909.165 us; speedup vs baseline: 1.7002x; 1.7002x over previous
//
#include <hip/hip_runtime.h>

// LinearRNNwithSoftExp on MI355X (gfx950)  T=1024, B=512, D=128, H=256.
// Round 2: kill register spills (round-1 WRITE_SIZE showed ~110 MB scratch).
// 256 wgs x 512 threads (8 waves). wg g owns batch rows {2g, 2g+1}.
// Wave w owns 32 output cols [32w, 32w+32): 2 alpha tiles + 2 hbar tiles of
// hh_w as persistent bf16 B-fragments (128 VGPRs) + 2 ih_w tiles (32 VGPRs).
// h-state: bf16 hi+lo split in LDS ping-pong (validated round 1, absmax 6.8e-3).
// data: staged 1 step ahead through LDS as bf16 by tid<256 (1 float/thread),
// removing the 32-reg prefetch buffer. One __syncthreads per step.

#define BB 512
#define DD 128
#define HH 256

typedef __attribute__((ext_vector_type(8))) short bf16x8;
typedef __attribute__((ext_vector_type(4))) float f32x4;

static __device__ __forceinline__ short f2bf(float f) {
    unsigned u = __float_as_uint(f);
    u += 0x7FFFu + ((u >> 16) & 1u);   // round-to-nearest-even
    return (short)(u >> 16);
}
static __device__ __forceinline__ float bf2f(short s) {
    return __uint_as_float(((unsigned)(unsigned short)s) << 16);
}
static __device__ __forceinline__ bf16x8 pack8(const float4 a, const float4 b) {
    bf16x8 v;
    v[0] = f2bf(a.x); v[1] = f2bf(a.y); v[2] = f2bf(a.z); v[3] = f2bf(a.w);
    v[4] = f2bf(b.x); v[5] = f2bf(b.y); v[6] = f2bf(b.z); v[7] = f2bf(b.w);
    return v;
}

__global__ __launch_bounds__(512, 2)
void rnn_fused(const float* __restrict__ data, const float* __restrict__ ih_w,
               const float* __restrict__ ih_b, const float* __restrict__ hh_w,
               const float* __restrict__ hh_b, const int* __restrict__ lengths,
               float* __restrict__ out)
{
    const int g    = blockIdx.x;
    const int tid  = threadIdx.x;
    const int w    = tid >> 6;     // wave 0..7
    const int lane = tid & 63;
    const int col  = lane & 15;    // MFMA n-col / A-row index
    const int quad = lane >> 4;    // k-quad

    // h state, bf16 split: [ping][hi/lo][row(2)][k(256)]
    // reads: 8 act lanes, 2 rows alias -> 2-way bank alias only (free).
    __shared__ short hbuf[2][2][2][HH];
    // data staging, bf16: [ping][row(2)][k(128)]
    __shared__ short dbuf[2][2][DD];

    // ---- persistent weight fragments in registers ----
    // whh[s*2+j][i]: s=0 alpha rows 32w+16j, s=1 hbar rows 256+32w+16j
    bf16x8 whh[4][8];
    #pragma unroll
    for (int s = 0; s < 2; ++s)
        #pragma unroll
        for (int j = 0; j < 2; ++j) {
            const int wrow = s*HH + 32*w + 16*j + col;
            const float* src = hh_w + wrow * HH;
            #pragma unroll
            for (int i = 0; i < 8; ++i) {
                const float4 a = *(const float4*)(src + i*32 + quad*8);
                const float4 b = *(const float4*)(src + i*32 + quad*8 + 4);
                whh[s*2 + j][i] = pack8(a, b);
            }
        }
    bf16x8 wih[2][4];
    #pragma unroll
    for (int j = 0; j < 2; ++j) {
        const int wrow = 32*w + 16*j + col;
        const float* src = ih_w + wrow * DD;
        #pragma unroll
        for (int i = 0; i < 4; ++i) {
            const float4 a = *(const float4*)(src + i*32 + quad*8);
            const float4 b = *(const float4*)(src + i*32 + quad*8 + 4);
            wih[j][i] = pack8(a, b);
        }
    }

    float bA[2], bH[2], bX[2];
    #pragma unroll
    for (int j = 0; j < 2; ++j) {
        bA[j] = hh_b[      32*w + 16*j + col];
        bH[j] = hh_b[HH  + 32*w + 16*j + col];
        bX[j] = ih_b[      32*w + 16*j + col];
    }

    const int L0 = lengths[2*g];
    const int L1 = lengths[2*g + 1];
    const int Lmax = (L0 > L1) ? L0 : L1;

    // ---- prologue: zero h, stage data[0] as bf16 ----
    for (int idx = tid; idx < 2*2*HH; idx += 512)
        ((short*)hbuf[0])[idx] = 0;
    if (tid < 256)
        ((short*)dbuf[0])[tid] = f2bf(data[(size_t)(2*g) * DD + tid]);
    __syncthreads();

    float  nh[2][2] = {{0.f,0.f},{0.f,0.f}};
    bf16x8 af[4] = {};   // h A-frags (non-act lanes stay 0 forever)
    bf16x8 dh[4] = {};   // data A-frags

    const bool act = (col < 2);          // only A-rows 0,1 are real

    for (int t = 0; t < Lmax; ++t) {
        const int p = t & 1;

        // ---- issue global load of data[t+1] (consumed next step) ----
        float vstage = 0.f;
        const bool stage = (tid < 256) && (t + 1 < Lmax);
        if (stage)
            vstage = data[((size_t)(t+1) * BB + 2*g) * DD + tid];

        // ---- recurrent matmul: hid = h @ hh_w^T + hh_b  (hi then lo pass) ----
        f32x4 racc[4];
        #pragma unroll
        for (int j = 0; j < 2; ++j) {
            f32x4 va = {bA[j], bA[j], bA[j], bA[j]}; racc[j]     = va;
            f32x4 vh = {bH[j], bH[j], bH[j], bH[j]}; racc[2 + j] = vh;
        }
        #pragma unroll
        for (int part = 0; part < 2; ++part) {          // hi, lo
            #pragma unroll
            for (int half = 0; half < 2; ++half) {      // k-frags 0-3, 4-7
                if (act) {
                    #pragma unroll
                    for (int i = 0; i < 4; ++i)
                        af[i] = *(const bf16x8*)
                            &hbuf[p][part][col][(half*4 + i)*32 + quad*8];
                }
                #pragma unroll
                for (int i = 0; i < 4; ++i)
                    #pragma unroll
                    for (int tt = 0; tt < 4; ++tt)
                        racc[tt] = __builtin_amdgcn_mfma_f32_16x16x32_bf16(
                            af[i], whh[tt][half*4 + i], racc[tt], 0, 0, 0);
            }
        }

        // ---- x-projection: data[t] @ ih_w^T + ih_b ----
        if (act) {
            #pragma unroll
            for (int i = 0; i < 4; ++i)
                dh[i] = *(const bf16x8*)&dbuf[p][col][i*32 + quad*8];
        }
        f32x4 xacc[2];
        #pragma unroll
        for (int j = 0; j < 2; ++j) {
            f32x4 v = {bX[j], bX[j], bX[j], bX[j]}; xacc[j] = v;
        }
        #pragma unroll
        for (int i = 0; i < 4; ++i)
            #pragma unroll
            for (int j = 0; j < 2; ++j)
                xacc[j] = __builtin_amdgcn_mfma_f32_16x16x32_bf16(
                    dh[i], wih[j][i], xacc[j], 0, 0, 0);

        // ---- epilogue: sigmoid, soft-exp gate, tanh, masked update ----
        // C/D layout: col = lane&15, row = quad*4 + reg; rows 0,1 in quad 0.
        #pragma unroll
        for (int j = 0; j < 2; ++j) {
            #pragma unroll
            for (int r = 0; r < 2; ++r) {
                const float a   = racc[j][r];
                const float hv  = racc[2 + j][r];
                const float e   = __builtin_amdgcn_exp2f(a * -1.4426950408889634f);
                const float inv = 1.0f + e;                    // exactly 1/alpha
                const float al  = __builtin_amdgcn_rcpf(inv);  // alpha
                const float pp  = __builtin_amdgcn_exp2f(al * hv);
                const float gg  = (pp - 1.0f) * inv + al;
                const float u   = xacc[j][r] + gg;
                const float t2  = __builtin_amdgcn_exp2f(u * 2.8853900817779268f);
                const float th  = 1.0f - 2.0f * __builtin_amdgcn_rcpf(1.0f + t2);
                const int   Lr  = r ? L1 : L0;
                const float v   = (t < Lr) ? th : nh[j][r];
                nh[j][r] = v;
                if (quad == 0) {
                    const short hi = f2bf(v);
                    const short lo = f2bf(v - bf2f(hi));
                    hbuf[1 - p][0][r][32*w + 16*j + col] = hi;
                    hbuf[1 - p][1][r][32*w + 16*j + col] = lo;
                }
            }
        }

        // ---- publish staged data[t+1] as bf16 (load long since landed) ----
        if (stage)
            ((short*)dbuf[1 - p])[tid] = f2bf(vstage);

        __syncthreads();
    }

    // ---- final hidden state -> out [1, B, H] fp32 ----
    if (quad == 0) {
        #pragma unroll
        for (int j = 0; j < 2; ++j)
            #pragma unroll
            for (int r = 0; r < 2; ++r)
                out[(size_t)(2*g + r) * HH + 32*w + 16*j + col] = nh[j][r];
    }
}

extern "C" void kernel_launch(void* const* d_in, const int* in_sizes, int n_in,
                              void* d_out, int out_size, void* d_ws, size_t ws_size,
                              hipStream_t stream) {
    const float* data    = (const float*)d_in[0];
    const float* ih_w    = (const float*)d_in[1];
    const float* ih_b    = (const float*)d_in[2];
    const float* hh_w    = (const float*)d_in[3];
    const float* hh_b    = (const float*)d_in[4];
    const int*   lengths = (const int*)d_in[5];
    float* out = (float*)d_out;

    (void)in_sizes; (void)n_in; (void)out_size; (void)d_ws; (void)ws_size;

    rnn_fused<<<dim3(BB / 2), dim3(512), 0, stream>>>(
        data, ih_w, ih_b, hh_w, hh_b, lengths, out);
}